// Round 11
// baseline (569.796 us; speedup 1.0000x reference)
//
#include <hip/hip_runtime.h>

#define NNODES 100000
#define NEDGES 1600000
#define DH 64
#define NG 512
#define DOUT 10
#define EPSV 1e-5f
#define SCAN_BLKS 391  // ceil(100000/256)
#define PCH 128        // nodes per pool block

typedef short bf16x8 __attribute__((ext_vector_type(8)));
typedef float f32x4 __attribute__((ext_vector_type(4)));

__device__ inline unsigned bf16_rne(float x) {
    unsigned u = __float_as_uint(x);
    return (u + 0x7fffu + ((u >> 16) & 1u)) >> 16;
}
__device__ inline float bflo(unsigned u) { return __uint_as_float(u << 16); }
__device__ inline float bfhi(unsigned u) { return __uint_as_float(u & 0xffff0000u); }

// ---------------------------------------------------------------- init / CSR build
__global__ void k_zero(int* __restrict__ cntdeg, float* __restrict__ pooled,
                       int* __restrict__ gstart, int* __restrict__ gend,
                       float* __restrict__ stats) {
    int i = blockIdx.x * 256 + threadIdx.x;
    if (i < NNODES) cntdeg[i] = 0;
    if (i < NG * DH) pooled[i] = 0.0f;
    if (i < NG) { gstart[i] = 0; gend[i] = 0; }
    if (i < 384) stats[i] = 0.0f;  // 3 layers x (sum,sumsq)
}

__global__ void k_count(const int* __restrict__ dstE, int* __restrict__ cntdeg) {
    int e2 = blockIdx.x * 256 + threadIdx.x;
    if (e2 * 2 + 1 < NEDGES) {
        int2 d = ((const int2*)dstE)[e2];
        atomicAdd(&cntdeg[d.x], 1);
        atomicAdd(&cntdeg[d.y], 1);
    } else if (e2 * 2 < NEDGES) {
        atomicAdd(&cntdeg[dstE[e2 * 2]], 1);
    }
}

// stage 1: per-block sums (+ dinv, + batch segment boundaries)
__global__ void k_scan1(const int* __restrict__ cntdeg, int* __restrict__ bsum,
                        float* __restrict__ dinv, const int* __restrict__ batch,
                        int* __restrict__ gstart, int* __restrict__ gend) {
    __shared__ int ls[256];
    int t = threadIdx.x, i = blockIdx.x * 256 + t;
    int v = (i < NNODES) ? cntdeg[i] : 0;
    if (i < NNODES) {
        dinv[i] = rsqrtf(1.0f + (float)v);
        int g = batch[i];
        if (i == 0 || batch[i - 1] != g) gstart[g] = i;
        if (i == NNODES - 1 || batch[i + 1] != g) gend[g] = i + 1;
    }
    ls[t] = v;
    __syncthreads();
#pragma unroll
    for (int off = 128; off > 0; off >>= 1) {
        if (t < off) ls[t] += ls[t + off];
        __syncthreads();
    }
    if (t == 0) bsum[blockIdx.x] = ls[0];
}

// stage 2: single-block scan of 391 block sums -> exclusive offsets
__global__ void __launch_bounds__(512) k_scan2(const int* __restrict__ bsum,
                                               int* __restrict__ boff) {
    __shared__ int ps[512];
    int t = threadIdx.x;
    int v = (t < SCAN_BLKS) ? bsum[t] : 0;
    ps[t] = v;
    __syncthreads();
#pragma unroll
    for (int off = 1; off < 512; off <<= 1) {
        int u = (t >= off) ? ps[t - off] : 0;
        __syncthreads();
        ps[t] += u;
        __syncthreads();
    }
    if (t < SCAN_BLKS) boff[t] = ps[t] - v;
}

// stage 3: per-block local scan + offset -> rowptr, cursor
__global__ void k_scan3(const int* __restrict__ cntdeg, const int* __restrict__ boff,
                        int* __restrict__ rowptr, int* __restrict__ cursor) {
    __shared__ int ps[256];
    int t = threadIdx.x, i = blockIdx.x * 256 + t;
    int v = (i < NNODES) ? cntdeg[i] : 0;
    ps[t] = v;
    __syncthreads();
#pragma unroll
    for (int off = 1; off < 256; off <<= 1) {
        int u = (t >= off) ? ps[t - off] : 0;
        __syncthreads();
        ps[t] += u;
        __syncthreads();
    }
    if (i < NNODES) {
        int ex = boff[blockIdx.x] + ps[t] - v;
        rowptr[i] = ex;
        cursor[i] = ex;
    }
    if (i == 0) rowptr[NNODES] = NEDGES;
}

// fill CSR slots: csr4[pos] = src only (norm recomputed in gather)
__global__ void k_fill(const int* __restrict__ srcE, const int* __restrict__ dstE,
                       int* __restrict__ cursor, int* __restrict__ csr4) {
    int e = blockIdx.x * 256 + threadIdx.x;
    if (e >= NEDGES) return;
    int s = srcE[e], d = dstE[e];
    int pos = atomicAdd(&cursor[d], 1);
    csr4[pos] = s;
}

// ---------------------------------------------------------------- W fragment prep
__global__ void k_wprep(const float* __restrict__ W0, const float* __restrict__ W1,
                        const float* __restrict__ W2, short* __restrict__ wf) {
    int t = blockIdx.x * 256 + threadIdx.x;  // [0, 1536)
    if (t >= 1536) return;
    int layer = t >> 9;
    int rem = t & 511;
    int ct = rem >> 7, ks = (rem >> 6) & 1, lane = rem & 63;
    const float* W = (layer == 0) ? W0 : (layer == 1) ? W1 : W2;
    short* hi = wf + layer * 8192 + rem * 8;
    short* lo = hi + 4096;
#pragma unroll
    for (int i = 0; i < 8; ++i) {
        int k = ks * 32 + ((lane >> 4) << 3) + i;
        int n = ct * 16 + (lane & 15);
        float v = W[k * 64 + n];
        unsigned h = bf16_rne(v);
        float fh = __uint_as_float(h << 16);
        unsigned l = bf16_rne(v - fh);
        hi[i] = (short)h;
        lo[i] = (short)l;
    }
}

// ---------------------------------------------------------------- MFMA GEMM (bf16 output)
template <int AFFINE>
__global__ void __launch_bounds__(256) k_mgemm(const float* __restrict__ in,
        const short* __restrict__ wf, const float* __restrict__ scale,
        const float* __restrict__ shift, unsigned short* __restrict__ out) {
    const int tid = threadIdx.x;
    const int wv = tid >> 6, l = tid & 63;
    const int r0 = blockIdx.x * 64 + wv * 16;
    const int row = r0 + (l & 15);
    const int kq = (l >> 4) << 3;  // 0,8,16,24

    float a[2][8];
    if (row < NNODES) {
        const float* rp = in + (size_t)row * 64 + kq;
        *(float4*)&a[0][0] = *(const float4*)(rp);
        *(float4*)&a[0][4] = *(const float4*)(rp + 4);
        *(float4*)&a[1][0] = *(const float4*)(rp + 32);
        *(float4*)&a[1][4] = *(const float4*)(rp + 36);
    } else {
#pragma unroll
        for (int ks = 0; ks < 2; ++ks)
#pragma unroll
            for (int i = 0; i < 8; ++i) a[ks][i] = 0.0f;
    }
    if (AFFINE) {
#pragma unroll
        for (int ks = 0; ks < 2; ++ks) {
            float4 sc0 = *(const float4*)(scale + kq + ks * 32);
            float4 sc1 = *(const float4*)(scale + kq + ks * 32 + 4);
            float4 sh0 = *(const float4*)(shift + kq + ks * 32);
            float4 sh1 = *(const float4*)(shift + kq + ks * 32 + 4);
            a[ks][0] = fmaxf(fmaf(a[ks][0], sc0.x, sh0.x), 0.0f);
            a[ks][1] = fmaxf(fmaf(a[ks][1], sc0.y, sh0.y), 0.0f);
            a[ks][2] = fmaxf(fmaf(a[ks][2], sc0.z, sh0.z), 0.0f);
            a[ks][3] = fmaxf(fmaf(a[ks][3], sc0.w, sh0.w), 0.0f);
            a[ks][4] = fmaxf(fmaf(a[ks][4], sc1.x, sh1.x), 0.0f);
            a[ks][5] = fmaxf(fmaf(a[ks][5], sc1.y, sh1.y), 0.0f);
            a[ks][6] = fmaxf(fmaf(a[ks][6], sc1.z, sh1.z), 0.0f);
            a[ks][7] = fmaxf(fmaf(a[ks][7], sc1.w, sh1.w), 0.0f);
        }
    }

    bf16x8 ah[2], al[2];
#pragma unroll
    for (int ks = 0; ks < 2; ++ks)
#pragma unroll
        for (int i = 0; i < 8; ++i) {
            unsigned h = bf16_rne(a[ks][i]);
            float fh = __uint_as_float(h << 16);
            ah[ks][i] = (short)h;
            al[ks][i] = (short)bf16_rne(a[ks][i] - fh);
        }

    const int rb = r0 + ((l >> 4) << 2);
    const int cb = l & 15;
#pragma unroll
    for (int ct = 0; ct < 4; ++ct) {
        const short* base = wf + (ct * 128 + l) * 8;
        bf16x8 wh0 = *(const bf16x8*)(base);
        bf16x8 wh1 = *(const bf16x8*)(base + 64 * 8);
        bf16x8 wl0 = *(const bf16x8*)(base + 4096);
        bf16x8 wl1 = *(const bf16x8*)(base + 4096 + 64 * 8);
        f32x4 acc = {0.0f, 0.0f, 0.0f, 0.0f};
        acc = __builtin_amdgcn_mfma_f32_16x16x32_bf16(ah[0], wh0, acc, 0, 0, 0);
        acc = __builtin_amdgcn_mfma_f32_16x16x32_bf16(ah[1], wh1, acc, 0, 0, 0);
        acc = __builtin_amdgcn_mfma_f32_16x16x32_bf16(al[0], wh0, acc, 0, 0, 0);
        acc = __builtin_amdgcn_mfma_f32_16x16x32_bf16(al[1], wh1, acc, 0, 0, 0);
        acc = __builtin_amdgcn_mfma_f32_16x16x32_bf16(ah[0], wl0, acc, 0, 0, 0);
        acc = __builtin_amdgcn_mfma_f32_16x16x32_bf16(ah[1], wl1, acc, 0, 0, 0);
        int n = ct * 16 + cb;
#pragma unroll
        for (int r = 0; r < 4; ++r)
            if (rb + r < NNODES) out[(size_t)(rb + r) * 64 + n] = (unsigned short)bf16_rne(acc[r]);
    }
}

// ---------------------------------------------------------------- gather (CSR src-only, bf16 h)
// agg[i] = bias + dv*( dv*h_i + sum_e dinv[src_e]*h[src_e] ),  dv = dinv[i]
__global__ void k_gather(const uint4* __restrict__ h, const int* __restrict__ csr4,
                         const int* __restrict__ rowptr, const float* __restrict__ dinv,
                         const float* __restrict__ bias, float* __restrict__ agg) {
    int t = blockIdx.x * 256 + threadIdx.x;
    int i = t >> 3, q = t & 7;
    if (i >= NNODES) return;
    float dv = dinv[i];
    uint4 hv = h[(size_t)i * 8 + q];
    float A[8], B[8];
    A[0] = bflo(hv.x) * dv; A[1] = bfhi(hv.x) * dv;
    A[2] = bflo(hv.y) * dv; A[3] = bfhi(hv.y) * dv;
    A[4] = bflo(hv.z) * dv; A[5] = bfhi(hv.z) * dv;
    A[6] = bflo(hv.w) * dv; A[7] = bfhi(hv.w) * dv;
#pragma unroll
    for (int k = 0; k < 8; ++k) B[k] = 0.0f;

    int e0 = rowptr[i], e1 = rowptr[i + 1];
    int e = e0;
    for (; e + 4 <= e1; e += 4) {
        int sa = csr4[e], sb = csr4[e + 1], sc = csr4[e + 2], sd = csr4[e + 3];
        float na = dinv[sa], nb = dinv[sb], nc = dinv[sc], nd = dinv[sd];
        uint4 va = h[(size_t)sa * 8 + q];
        uint4 vb = h[(size_t)sb * 8 + q];
        uint4 vc = h[(size_t)sc * 8 + q];
        uint4 vd = h[(size_t)sd * 8 + q];
        A[0] = fmaf(bflo(va.x), na, A[0]); A[1] = fmaf(bfhi(va.x), na, A[1]);
        A[2] = fmaf(bflo(va.y), na, A[2]); A[3] = fmaf(bfhi(va.y), na, A[3]);
        A[4] = fmaf(bflo(va.z), na, A[4]); A[5] = fmaf(bfhi(va.z), na, A[5]);
        A[6] = fmaf(bflo(va.w), na, A[6]); A[7] = fmaf(bfhi(va.w), na, A[7]);
        B[0] = fmaf(bflo(vb.x), nb, B[0]); B[1] = fmaf(bfhi(vb.x), nb, B[1]);
        B[2] = fmaf(bflo(vb.y), nb, B[2]); B[3] = fmaf(bfhi(vb.y), nb, B[3]);
        B[4] = fmaf(bflo(vb.z), nb, B[4]); B[5] = fmaf(bfhi(vb.z), nb, B[5]);
        B[6] = fmaf(bflo(vb.w), nb, B[6]); B[7] = fmaf(bfhi(vb.w), nb, B[7]);
        A[0] = fmaf(bflo(vc.x), nc, A[0]); A[1] = fmaf(bfhi(vc.x), nc, A[1]);
        A[2] = fmaf(bflo(vc.y), nc, A[2]); A[3] = fmaf(bfhi(vc.y), nc, A[3]);
        A[4] = fmaf(bflo(vc.z), nc, A[4]); A[5] = fmaf(bfhi(vc.z), nc, A[5]);
        A[6] = fmaf(bflo(vc.w), nc, A[6]); A[7] = fmaf(bfhi(vc.w), nc, A[7]);
        B[0] = fmaf(bflo(vd.x), nd, B[0]); B[1] = fmaf(bfhi(vd.x), nd, B[1]);
        B[2] = fmaf(bflo(vd.y), nd, B[2]); B[3] = fmaf(bfhi(vd.y), nd, B[3]);
        B[4] = fmaf(bflo(vd.z), nd, B[4]); B[5] = fmaf(bfhi(vd.z), nd, B[5]);
        B[6] = fmaf(bflo(vd.w), nd, B[6]); B[7] = fmaf(bfhi(vd.w), nd, B[7]);
    }
    for (; e + 2 <= e1; e += 2) {
        int sa = csr4[e], sb = csr4[e + 1];
        float na = dinv[sa], nb = dinv[sb];
        uint4 va = h[(size_t)sa * 8 + q];
        uint4 vb = h[(size_t)sb * 8 + q];
        A[0] = fmaf(bflo(va.x), na, A[0]); A[1] = fmaf(bfhi(va.x), na, A[1]);
        A[2] = fmaf(bflo(va.y), na, A[2]); A[3] = fmaf(bfhi(va.y), na, A[3]);
        A[4] = fmaf(bflo(va.z), na, A[4]); A[5] = fmaf(bfhi(va.z), na, A[5]);
        A[6] = fmaf(bflo(va.w), na, A[6]); A[7] = fmaf(bfhi(va.w), na, A[7]);
        B[0] = fmaf(bflo(vb.x), nb, B[0]); B[1] = fmaf(bfhi(vb.x), nb, B[1]);
        B[2] = fmaf(bflo(vb.y), nb, B[2]); B[3] = fmaf(bfhi(vb.y), nb, B[3]);
        B[4] = fmaf(bflo(vb.z), nb, B[4]); B[5] = fmaf(bfhi(vb.z), nb, B[5]);
        B[6] = fmaf(bflo(vb.w), nb, B[6]); B[7] = fmaf(bfhi(vb.w), nb, B[7]);
    }
    if (e < e1) {
        int sa = csr4[e];
        float na = dinv[sa];
        uint4 va = h[(size_t)sa * 8 + q];
        A[0] = fmaf(bflo(va.x), na, A[0]); A[1] = fmaf(bfhi(va.x), na, A[1]);
        A[2] = fmaf(bflo(va.y), na, A[2]); A[3] = fmaf(bfhi(va.y), na, A[3]);
        A[4] = fmaf(bflo(va.z), na, A[4]); A[5] = fmaf(bfhi(va.z), na, A[5]);
        A[6] = fmaf(bflo(va.w), na, A[6]); A[7] = fmaf(bfhi(va.w), na, A[7]);
    }
    float4 b0 = ((const float4*)bias)[q * 2];
    float4 b1 = ((const float4*)bias)[q * 2 + 1];
    float4 r0, r1;
    r0.x = fmaf(A[0] + B[0], dv, b0.x); r0.y = fmaf(A[1] + B[1], dv, b0.y);
    r0.z = fmaf(A[2] + B[2], dv, b0.z); r0.w = fmaf(A[3] + B[3], dv, b0.w);
    r1.x = fmaf(A[4] + B[4], dv, b1.x); r1.y = fmaf(A[5] + B[5], dv, b1.y);
    r1.z = fmaf(A[6] + B[6], dv, b1.z); r1.w = fmaf(A[7] + B[7], dv, b1.w);
    ((float4*)agg)[(size_t)i * 16 + q * 2] = r0;
    ((float4*)agg)[(size_t)i * 16 + q * 2 + 1] = r1;
}

// ---------------------------------------------------------------- BN stats (float4 vectorized)
__global__ void k_stats(const float* __restrict__ agg, float* __restrict__ stats) {
    const int tid = threadIdx.x;
    const int c4 = (tid & 15) * 4;      // feature group
    const int rg = tid >> 4;            // row subgroup 0..15
    float s0 = 0, s1 = 0, s2 = 0, s3 = 0;
    float q0 = 0, q1 = 0, q2 = 0, q3 = 0;
    for (int r = blockIdx.x * 16 + rg; r < NNODES; r += gridDim.x * 16) {
        float4 v = *(const float4*)(agg + (size_t)r * 64 + c4);
        s0 += v.x; s1 += v.y; s2 += v.z; s3 += v.w;
        q0 = fmaf(v.x, v.x, q0); q1 = fmaf(v.y, v.y, q1);
        q2 = fmaf(v.z, v.z, q2); q3 = fmaf(v.w, v.w, q3);
    }
    __shared__ float ls[16 * 64], lq[16 * 64];
    ls[rg * 64 + c4 + 0] = s0; ls[rg * 64 + c4 + 1] = s1;
    ls[rg * 64 + c4 + 2] = s2; ls[rg * 64 + c4 + 3] = s3;
    lq[rg * 64 + c4 + 0] = q0; lq[rg * 64 + c4 + 1] = q1;
    lq[rg * 64 + c4 + 2] = q2; lq[rg * 64 + c4 + 3] = q3;
    __syncthreads();
    if (tid < 64) {
        float s = 0, q = 0;
#pragma unroll
        for (int g = 0; g < 16; ++g) {
            s += ls[g * 64 + tid];
            q += lq[g * 64 + tid];
        }
        unsafeAtomicAdd(&stats[tid], s);
        unsafeAtomicAdd(&stats[64 + tid], q);
    }
}

__global__ void k_bnparams(const float* __restrict__ stats, const float* __restrict__ g,
                           const float* __restrict__ be, float* __restrict__ scale,
                           float* __restrict__ shift) {
    int c = threadIdx.x;
    if (c < 64) {
        float mu = stats[c] * (1.0f / NNODES);
        float var = stats[64 + c] * (1.0f / NNODES) - mu * mu;
        float sc = g[c] * rsqrtf(var + EPSV);
        scale[c] = sc;
        shift[c] = fmaf(-mu, sc, be[c]);
    }
}

// ---------------------------------------------------------------- pool (sorted-batch run accumulation)
__global__ void k_pool(const float* __restrict__ agg, const float* __restrict__ scale,
                       const float* __restrict__ shift, const int* __restrict__ batch,
                       float* __restrict__ pooled) {
    const int tid = threadIdx.x;
    const int c = tid & 63, r = tid >> 6;
    const int i0 = blockIdx.x * PCH;
    const float sc = scale[c], sh = shift[c];
    float acc = 0.0f;
    int cur = -1;
#pragma unroll 4
    for (int k = 0; k < PCH / 4; ++k) {
        int i = i0 + k * 4 + r;
        if (i >= NNODES) break;
        int g = batch[i];
        if (g != cur) {
            if (cur >= 0) unsafeAtomicAdd(&pooled[cur * 64 + c], acc);
            acc = 0.0f;
            cur = g;
        }
        acc += fmaxf(fmaf(agg[(size_t)i * 64 + c], sc, sh), 0.0f);
    }
    if (cur >= 0) unsafeAtomicAdd(&pooled[cur * 64 + c], acc);
}

__global__ void k_final(const float* __restrict__ pooled, const int* __restrict__ gstart,
                        const int* __restrict__ gend, const float* __restrict__ Wfc,
                        const float* __restrict__ bfc, float* __restrict__ out) {
    __shared__ float p[64];
    __shared__ float ic;
    int g = blockIdx.x, tid = threadIdx.x;
    p[tid] = pooled[(size_t)g * 64 + tid];
    if (tid == 0) ic = 1.0f / fmaxf((float)(gend[g] - gstart[g]), 1.0f);
    __syncthreads();
    if (tid < DOUT) {
        float a = bfc[tid];
#pragma unroll 8
        for (int c = 0; c < 64; ++c) a = fmaf(p[c] * ic, Wfc[c * DOUT + tid], a);
        out[g * DOUT + tid] = a;
    }
}

// ---------------------------------------------------------------- launch
extern "C" void kernel_launch(void* const* d_in, const int* in_sizes, int n_in,
                              void* d_out, int out_size, void* d_ws, size_t ws_size,
                              hipStream_t stream) {
    const float* x = (const float*)d_in[0];
    const int* ei = (const int*)d_in[1];
    const int* batch = (const int*)d_in[2];
    const int* srcE = ei;
    const int* dstE = ei + NEDGES;
    const float* W[3] = {(const float*)d_in[3], (const float*)d_in[7], (const float*)d_in[11]};
    const float* B[3] = {(const float*)d_in[4], (const float*)d_in[8], (const float*)d_in[12]};
    const float* Gm[3] = {(const float*)d_in[5], (const float*)d_in[9], (const float*)d_in[13]};
    const float* Be[3] = {(const float*)d_in[6], (const float*)d_in[10], (const float*)d_in[14]};
    const float* Wfc = (const float*)d_in[15];
    const float* bfc = (const float*)d_in[16];
    float* out = (float*)d_out;

    float* f = (float*)d_ws;
    float* dinv = f;                            // [0, 100000)
    int* cntdeg = (int*)(f + 100000);           // [100000, 200000)
    int* rowptr = (int*)(f + 200000);           // [200000, 300016)
    int* cursor = (int*)(f + 300016);           // [300016, 400016)
    int* csr4 = (int*)(f + 400016);             // [400016, 2000016)  1.6M ints
    unsigned short* h = (unsigned short*)(f + 2000016);  // 6.4M bf16 = 3.2M floats: [2000016, 5200016)
    float* agg = f + 5200016;                   // [5200016, 11600016)  6.4M floats
    float* stats = agg + (size_t)NNODES * DH;   // 384 (3 layers x 128)
    float* scale = stats + 384;                 // 64
    float* shift = scale + 64;                  // 64
    float* pooled = shift + 64;                 // 32768
    int* gstart = (int*)(pooled + NG * DH);     // 512
    int* gend = gstart + NG;                    // 512
    short* wf = (short*)(gend + NG);            // 3*8192 shorts
    int* bsum = (int*)((short*)wf + 24576);     // 400
    int* boff = bsum + 400;                     // 400

    k_zero<<<(NNODES + 255) / 256, 256, 0, stream>>>(cntdeg, pooled, gstart, gend, stats);
    k_count<<<(NEDGES / 2 + 255) / 256, 256, 0, stream>>>(dstE, cntdeg);
    k_scan1<<<SCAN_BLKS, 256, 0, stream>>>(cntdeg, bsum, dinv, batch, gstart, gend);
    k_scan2<<<1, 512, 0, stream>>>(bsum, boff);
    k_scan3<<<SCAN_BLKS, 256, 0, stream>>>(cntdeg, boff, rowptr, cursor);
    k_fill<<<(NEDGES + 255) / 256, 256, 0, stream>>>(srcE, dstE, cursor, csr4);
    k_wprep<<<6, 256, 0, stream>>>(W[0], W[1], W[2], wf);

    const int gemm_grid = (NNODES + 63) / 64;
    for (int l = 0; l < 3; ++l) {
        const float* in = (l == 0) ? x : agg;
        if (l == 0)
            k_mgemm<0><<<gemm_grid, 256, 0, stream>>>(in, wf + l * 8192, scale, shift, h);
        else
            k_mgemm<1><<<gemm_grid, 256, 0, stream>>>(in, wf + l * 8192, scale, shift, h);
        k_gather<<<(NNODES * 8 + 255) / 256, 256, 0, stream>>>((const uint4*)h, csr4, rowptr, dinv, B[l], agg);
        k_stats<<<512, 256, 0, stream>>>(agg, stats + l * 128);
        k_bnparams<<<1, 64, 0, stream>>>(stats + l * 128, Gm[l], Be[l], scale, shift);
    }

    k_pool<<<(NNODES + PCH - 1) / PCH, 256, 0, stream>>>(agg, scale, shift, batch, pooled);
    k_final<<<NG, 64, 0, stream>>>(pooled, gstart, gend, Wfc, bfc, out);
}

// Round 12
// 490.726 us; speedup vs baseline: 1.1611x; 1.1611x over previous
//
#include <hip/hip_runtime.h>

#define NNODES 100000
#define NEDGES 1600000
#define DH 64
#define NG 512
#define DOUT 10
#define EPSV 1e-5f
#define SCAN_BLKS 391  // ceil(100000/256)
#define PCH 128        // nodes per pool block
#define NB 196         // dst buckets: ceil(100000/512)
#define EBLK 4096      // edges per histogram block
#define NEB 391        // ceil(NEDGES/EBLK)

typedef short bf16x8 __attribute__((ext_vector_type(8)));
typedef float f32x4 __attribute__((ext_vector_type(4)));

__device__ inline unsigned bf16_rne(float x) {
    unsigned u = __float_as_uint(x);
    return (u + 0x7fffu + ((u >> 16) & 1u)) >> 16;
}
__device__ inline float bflo(unsigned u) { return __uint_as_float(u << 16); }
__device__ inline float bfhi(unsigned u) { return __uint_as_float(u & 0xffff0000u); }

// ---------------------------------------------------------------- init / degree
__global__ void k_zero(int* __restrict__ cntdeg, float* __restrict__ pooled,
                       int* __restrict__ gstart, int* __restrict__ gend,
                       float* __restrict__ stats) {
    int i = blockIdx.x * 256 + threadIdx.x;
    if (i < NNODES) cntdeg[i] = 0;
    if (i < NG * DH) pooled[i] = 0.0f;
    if (i < NG) { gstart[i] = 0; gend[i] = 0; }
    if (i < 384) stats[i] = 0.0f;  // 3 layers x (sum,sumsq)
}

__global__ void k_count(const int* __restrict__ dstE, int* __restrict__ cntdeg) {
    int e2 = blockIdx.x * 256 + threadIdx.x;
    if (e2 * 2 + 1 < NEDGES) {
        int2 d = ((const int2*)dstE)[e2];
        atomicAdd(&cntdeg[d.x], 1);
        atomicAdd(&cntdeg[d.y], 1);
    } else if (e2 * 2 < NEDGES) {
        atomicAdd(&cntdeg[dstE[e2 * 2]], 1);
    }
}

// stage 1: per-block sums (+ dinv, + batch segment boundaries)
__global__ void k_scan1(const int* __restrict__ cntdeg, int* __restrict__ bsum,
                        float* __restrict__ dinv, const int* __restrict__ batch,
                        int* __restrict__ gstart, int* __restrict__ gend) {
    __shared__ int ls[256];
    int t = threadIdx.x, i = blockIdx.x * 256 + t;
    int v = (i < NNODES) ? cntdeg[i] : 0;
    if (i < NNODES) {
        dinv[i] = rsqrtf(1.0f + (float)v);
        int g = batch[i];
        if (i == 0 || batch[i - 1] != g) gstart[g] = i;
        if (i == NNODES - 1 || batch[i + 1] != g) gend[g] = i + 1;
    }
    ls[t] = v;
    __syncthreads();
#pragma unroll
    for (int off = 128; off > 0; off >>= 1) {
        if (t < off) ls[t] += ls[t + off];
        __syncthreads();
    }
    if (t == 0) bsum[blockIdx.x] = ls[0];
}

// stage 2: single-block scan of 391 block sums -> exclusive offsets
__global__ void __launch_bounds__(512) k_scan2(const int* __restrict__ bsum,
                                               int* __restrict__ boff) {
    __shared__ int ps[512];
    int t = threadIdx.x;
    int v = (t < SCAN_BLKS) ? bsum[t] : 0;
    ps[t] = v;
    __syncthreads();
#pragma unroll
    for (int off = 1; off < 512; off <<= 1) {
        int u = (t >= off) ? ps[t - off] : 0;
        __syncthreads();
        ps[t] += u;
        __syncthreads();
    }
    if (t < SCAN_BLKS) boff[t] = ps[t] - v;
}

// stage 3: per-block local scan + offset -> rowptr
__global__ void k_scan3(const int* __restrict__ cntdeg, const int* __restrict__ boff,
                        int* __restrict__ rowptr) {
    __shared__ int ps[256];
    int t = threadIdx.x, i = blockIdx.x * 256 + t;
    int v = (i < NNODES) ? cntdeg[i] : 0;
    ps[t] = v;
    __syncthreads();
#pragma unroll
    for (int off = 1; off < 256; off <<= 1) {
        int u = (t >= off) ? ps[t - off] : 0;
        __syncthreads();
        ps[t] += u;
        __syncthreads();
    }
    if (i < NNODES) rowptr[i] = boff[blockIdx.x] + ps[t] - v;
    if (i == 0) rowptr[NNODES] = NEDGES;
}

// ---------------------------------------------------------------- bucketed CSR fill
// pass A: per edge-block histogram over 196 dst-buckets
__global__ void k_hist(const int* __restrict__ dstE, int* __restrict__ bhist) {
    __shared__ int lc[NB];
    int t = threadIdx.x, eb = blockIdx.x;
    for (int j = t; j < NB; j += 256) lc[j] = 0;
    __syncthreads();
    int e0 = eb * EBLK;
#pragma unroll
    for (int k = 0; k < EBLK / 256; ++k) {
        int e = e0 + k * 256 + t;
        if (e < NEDGES) atomicAdd(&lc[dstE[e] >> 9], 1);
    }
    __syncthreads();
    for (int j = t; j < NB; j += 256) bhist[eb * NB + j] = lc[j];
}

// pass B: per-bucket exclusive scan of block counts; base from rowptr
__global__ void __launch_bounds__(512) k_bscan(const int* __restrict__ bhist,
                                               const int* __restrict__ rowptr,
                                               int* __restrict__ boffs) {
    __shared__ int ps[512];
    int b = blockIdx.x, t = threadIdx.x;
    int v = (t < NEB) ? bhist[t * NB + b] : 0;
    ps[t] = v;
    __syncthreads();
#pragma unroll
    for (int off = 1; off < 512; off <<= 1) {
        int u = (t >= off) ? ps[t - off] : 0;
        __syncthreads();
        ps[t] += u;
        __syncthreads();
    }
    if (t < NEB) boffs[t * NB + b] = rowptr[b << 9] + ps[t] - v;
}

// pass C: scatter (src,dst) into bucket-contiguous staging (runs ~21 entries)
__global__ void k_bucket(const int* __restrict__ srcE, const int* __restrict__ dstE,
                         const int* __restrict__ boffs, int2* __restrict__ staged) {
    __shared__ int lc[NB];
    __shared__ int lb[NB];
    int t = threadIdx.x, eb = blockIdx.x;
    for (int j = t; j < NB; j += 256) { lc[j] = 0; lb[j] = boffs[eb * NB + j]; }
    __syncthreads();
    int e0 = eb * EBLK;
#pragma unroll
    for (int k = 0; k < EBLK / 256; ++k) {
        int e = e0 + k * 256 + t;
        if (e < NEDGES) {
            int d = dstE[e], s = srcE[e];
            int b = d >> 9;
            int slot = atomicAdd(&lc[b], 1);
            staged[lb[b] + slot] = make_int2(s, d);
        }
    }
}

// pass D: bucket-owned final fill. All writes to a bucket's 32KB CSR window come
// from one CU -> L2-resident, no cross-XCD line sharing. Cursors live in LDS.
__global__ void k_fill2(const int2* __restrict__ staged, const int* __restrict__ rowptr,
                        int* __restrict__ csr4) {
    __shared__ int cur[512];
    int b = blockIdx.x, t = threadIdx.x;
    int n0 = b << 9;
    int nCnt = NNODES - n0;
    if (nCnt > 512) nCnt = 512;
    for (int j = t; j < nCnt; j += 256) cur[j] = rowptr[n0 + j];
    __syncthreads();
    int base = rowptr[n0], end = rowptr[n0 + nCnt];
    for (int e = base + t; e < end; e += 256) {
        int2 sd = staged[e];
        int pos = atomicAdd(&cur[sd.y - n0], 1);
        csr4[pos] = sd.x;
    }
}

// ---------------------------------------------------------------- W fragment prep
__global__ void k_wprep(const float* __restrict__ W0, const float* __restrict__ W1,
                        const float* __restrict__ W2, short* __restrict__ wf) {
    int t = blockIdx.x * 256 + threadIdx.x;  // [0, 1536)
    if (t >= 1536) return;
    int layer = t >> 9;
    int rem = t & 511;
    int ct = rem >> 7, ks = (rem >> 6) & 1, lane = rem & 63;
    const float* W = (layer == 0) ? W0 : (layer == 1) ? W1 : W2;
    short* hi = wf + layer * 8192 + rem * 8;
    short* lo = hi + 4096;
#pragma unroll
    for (int i = 0; i < 8; ++i) {
        int k = ks * 32 + ((lane >> 4) << 3) + i;
        int n = ct * 16 + (lane & 15);
        float v = W[k * 64 + n];
        unsigned h = bf16_rne(v);
        float fh = __uint_as_float(h << 16);
        unsigned l = bf16_rne(v - fh);
        hi[i] = (short)h;
        lo[i] = (short)l;
    }
}

// ---------------------------------------------------------------- MFMA GEMM (bf16 output)
template <int AFFINE>
__global__ void __launch_bounds__(256) k_mgemm(const float* __restrict__ in,
        const short* __restrict__ wf, const float* __restrict__ scale,
        const float* __restrict__ shift, unsigned short* __restrict__ out) {
    const int tid = threadIdx.x;
    const int wv = tid >> 6, l = tid & 63;
    const int r0 = blockIdx.x * 64 + wv * 16;
    const int row = r0 + (l & 15);
    const int kq = (l >> 4) << 3;  // 0,8,16,24

    float a[2][8];
    if (row < NNODES) {
        const float* rp = in + (size_t)row * 64 + kq;
        *(float4*)&a[0][0] = *(const float4*)(rp);
        *(float4*)&a[0][4] = *(const float4*)(rp + 4);
        *(float4*)&a[1][0] = *(const float4*)(rp + 32);
        *(float4*)&a[1][4] = *(const float4*)(rp + 36);
    } else {
#pragma unroll
        for (int ks = 0; ks < 2; ++ks)
#pragma unroll
            for (int i = 0; i < 8; ++i) a[ks][i] = 0.0f;
    }
    if (AFFINE) {
#pragma unroll
        for (int ks = 0; ks < 2; ++ks) {
            float4 sc0 = *(const float4*)(scale + kq + ks * 32);
            float4 sc1 = *(const float4*)(scale + kq + ks * 32 + 4);
            float4 sh0 = *(const float4*)(shift + kq + ks * 32);
            float4 sh1 = *(const float4*)(shift + kq + ks * 32 + 4);
            a[ks][0] = fmaxf(fmaf(a[ks][0], sc0.x, sh0.x), 0.0f);
            a[ks][1] = fmaxf(fmaf(a[ks][1], sc0.y, sh0.y), 0.0f);
            a[ks][2] = fmaxf(fmaf(a[ks][2], sc0.z, sh0.z), 0.0f);
            a[ks][3] = fmaxf(fmaf(a[ks][3], sc0.w, sh0.w), 0.0f);
            a[ks][4] = fmaxf(fmaf(a[ks][4], sc1.x, sh1.x), 0.0f);
            a[ks][5] = fmaxf(fmaf(a[ks][5], sc1.y, sh1.y), 0.0f);
            a[ks][6] = fmaxf(fmaf(a[ks][6], sc1.z, sh1.z), 0.0f);
            a[ks][7] = fmaxf(fmaf(a[ks][7], sc1.w, sh1.w), 0.0f);
        }
    }

    bf16x8 ah[2], al[2];
#pragma unroll
    for (int ks = 0; ks < 2; ++ks)
#pragma unroll
        for (int i = 0; i < 8; ++i) {
            unsigned h = bf16_rne(a[ks][i]);
            float fh = __uint_as_float(h << 16);
            ah[ks][i] = (short)h;
            al[ks][i] = (short)bf16_rne(a[ks][i] - fh);
        }

    const int rb = r0 + ((l >> 4) << 2);
    const int cb = l & 15;
#pragma unroll
    for (int ct = 0; ct < 4; ++ct) {
        const short* base = wf + (ct * 128 + l) * 8;
        bf16x8 wh0 = *(const bf16x8*)(base);
        bf16x8 wh1 = *(const bf16x8*)(base + 64 * 8);
        bf16x8 wl0 = *(const bf16x8*)(base + 4096);
        bf16x8 wl1 = *(const bf16x8*)(base + 4096 + 64 * 8);
        f32x4 acc = {0.0f, 0.0f, 0.0f, 0.0f};
        acc = __builtin_amdgcn_mfma_f32_16x16x32_bf16(ah[0], wh0, acc, 0, 0, 0);
        acc = __builtin_amdgcn_mfma_f32_16x16x32_bf16(ah[1], wh1, acc, 0, 0, 0);
        acc = __builtin_amdgcn_mfma_f32_16x16x32_bf16(al[0], wh0, acc, 0, 0, 0);
        acc = __builtin_amdgcn_mfma_f32_16x16x32_bf16(al[1], wh1, acc, 0, 0, 0);
        acc = __builtin_amdgcn_mfma_f32_16x16x32_bf16(ah[0], wl0, acc, 0, 0, 0);
        acc = __builtin_amdgcn_mfma_f32_16x16x32_bf16(ah[1], wl1, acc, 0, 0, 0);
        int n = ct * 16 + cb;
#pragma unroll
        for (int r = 0; r < 4; ++r)
            if (rb + r < NNODES) out[(size_t)(rb + r) * 64 + n] = (unsigned short)bf16_rne(acc[r]);
    }
}

// ---------------------------------------------------------------- gather (CSR src-only, bf16 h)
// agg[i] = bias + dv*( dv*h_i + sum_e dinv[src_e]*h[src_e] ),  dv = dinv[i]
__global__ void k_gather(const uint4* __restrict__ h, const int* __restrict__ csr4,
                         const int* __restrict__ rowptr, const float* __restrict__ dinv,
                         const float* __restrict__ bias, float* __restrict__ agg) {
    int t = blockIdx.x * 256 + threadIdx.x;
    int i = t >> 3, q = t & 7;
    if (i >= NNODES) return;
    float dv = dinv[i];
    uint4 hv = h[(size_t)i * 8 + q];
    float A[8], B[8];
    A[0] = bflo(hv.x) * dv; A[1] = bfhi(hv.x) * dv;
    A[2] = bflo(hv.y) * dv; A[3] = bfhi(hv.y) * dv;
    A[4] = bflo(hv.z) * dv; A[5] = bfhi(hv.z) * dv;
    A[6] = bflo(hv.w) * dv; A[7] = bfhi(hv.w) * dv;
#pragma unroll
    for (int k = 0; k < 8; ++k) B[k] = 0.0f;

    int e0 = rowptr[i], e1 = rowptr[i + 1];
    int e = e0;
    for (; e + 4 <= e1; e += 4) {
        int sa = csr4[e], sb = csr4[e + 1], sc = csr4[e + 2], sd = csr4[e + 3];
        float na = dinv[sa], nb = dinv[sb], nc = dinv[sc], nd = dinv[sd];
        uint4 va = h[(size_t)sa * 8 + q];
        uint4 vb = h[(size_t)sb * 8 + q];
        uint4 vc = h[(size_t)sc * 8 + q];
        uint4 vd = h[(size_t)sd * 8 + q];
        A[0] = fmaf(bflo(va.x), na, A[0]); A[1] = fmaf(bfhi(va.x), na, A[1]);
        A[2] = fmaf(bflo(va.y), na, A[2]); A[3] = fmaf(bfhi(va.y), na, A[3]);
        A[4] = fmaf(bflo(va.z), na, A[4]); A[5] = fmaf(bfhi(va.z), na, A[5]);
        A[6] = fmaf(bflo(va.w), na, A[6]); A[7] = fmaf(bfhi(va.w), na, A[7]);
        B[0] = fmaf(bflo(vb.x), nb, B[0]); B[1] = fmaf(bfhi(vb.x), nb, B[1]);
        B[2] = fmaf(bflo(vb.y), nb, B[2]); B[3] = fmaf(bfhi(vb.y), nb, B[3]);
        B[4] = fmaf(bflo(vb.z), nb, B[4]); B[5] = fmaf(bfhi(vb.z), nb, B[5]);
        B[6] = fmaf(bflo(vb.w), nb, B[6]); B[7] = fmaf(bfhi(vb.w), nb, B[7]);
        A[0] = fmaf(bflo(vc.x), nc, A[0]); A[1] = fmaf(bfhi(vc.x), nc, A[1]);
        A[2] = fmaf(bflo(vc.y), nc, A[2]); A[3] = fmaf(bfhi(vc.y), nc, A[3]);
        A[4] = fmaf(bflo(vc.z), nc, A[4]); A[5] = fmaf(bfhi(vc.z), nc, A[5]);
        A[6] = fmaf(bflo(vc.w), nc, A[6]); A[7] = fmaf(bfhi(vc.w), nc, A[7]);
        B[0] = fmaf(bflo(vd.x), nd, B[0]); B[1] = fmaf(bfhi(vd.x), nd, B[1]);
        B[2] = fmaf(bflo(vd.y), nd, B[2]); B[3] = fmaf(bfhi(vd.y), nd, B[3]);
        B[4] = fmaf(bflo(vd.z), nd, B[4]); B[5] = fmaf(bfhi(vd.z), nd, B[5]);
        B[6] = fmaf(bflo(vd.w), nd, B[6]); B[7] = fmaf(bfhi(vd.w), nd, B[7]);
    }
    for (; e + 2 <= e1; e += 2) {
        int sa = csr4[e], sb = csr4[e + 1];
        float na = dinv[sa], nb = dinv[sb];
        uint4 va = h[(size_t)sa * 8 + q];
        uint4 vb = h[(size_t)sb * 8 + q];
        A[0] = fmaf(bflo(va.x), na, A[0]); A[1] = fmaf(bfhi(va.x), na, A[1]);
        A[2] = fmaf(bflo(va.y), na, A[2]); A[3] = fmaf(bfhi(va.y), na, A[3]);
        A[4] = fmaf(bflo(va.z), na, A[4]); A[5] = fmaf(bfhi(va.z), na, A[5]);
        A[6] = fmaf(bflo(va.w), na, A[6]); A[7] = fmaf(bfhi(va.w), na, A[7]);
        B[0] = fmaf(bflo(vb.x), nb, B[0]); B[1] = fmaf(bfhi(vb.x), nb, B[1]);
        B[2] = fmaf(bflo(vb.y), nb, B[2]); B[3] = fmaf(bfhi(vb.y), nb, B[3]);
        B[4] = fmaf(bflo(vb.z), nb, B[4]); B[5] = fmaf(bfhi(vb.z), nb, B[5]);
        B[6] = fmaf(bflo(vb.w), nb, B[6]); B[7] = fmaf(bfhi(vb.w), nb, B[7]);
    }
    if (e < e1) {
        int sa = csr4[e];
        float na = dinv[sa];
        uint4 va = h[(size_t)sa * 8 + q];
        A[0] = fmaf(bflo(va.x), na, A[0]); A[1] = fmaf(bfhi(va.x), na, A[1]);
        A[2] = fmaf(bflo(va.y), na, A[2]); A[3] = fmaf(bfhi(va.y), na, A[3]);
        A[4] = fmaf(bflo(va.z), na, A[4]); A[5] = fmaf(bfhi(va.z), na, A[5]);
        A[6] = fmaf(bflo(va.w), na, A[6]); A[7] = fmaf(bfhi(va.w), na, A[7]);
    }
    float4 b0 = ((const float4*)bias)[q * 2];
    float4 b1 = ((const float4*)bias)[q * 2 + 1];
    float4 r0, r1;
    r0.x = fmaf(A[0] + B[0], dv, b0.x); r0.y = fmaf(A[1] + B[1], dv, b0.y);
    r0.z = fmaf(A[2] + B[2], dv, b0.z); r0.w = fmaf(A[3] + B[3], dv, b0.w);
    r1.x = fmaf(A[4] + B[4], dv, b1.x); r1.y = fmaf(A[5] + B[5], dv, b1.y);
    r1.z = fmaf(A[6] + B[6], dv, b1.z); r1.w = fmaf(A[7] + B[7], dv, b1.w);
    ((float4*)agg)[(size_t)i * 16 + q * 2] = r0;
    ((float4*)agg)[(size_t)i * 16 + q * 2 + 1] = r1;
}

// ---------------------------------------------------------------- BN stats (float4 vectorized)
__global__ void k_stats(const float* __restrict__ agg, float* __restrict__ stats) {
    const int tid = threadIdx.x;
    const int c4 = (tid & 15) * 4;      // feature group
    const int rg = tid >> 4;            // row subgroup 0..15
    float s0 = 0, s1 = 0, s2 = 0, s3 = 0;
    float q0 = 0, q1 = 0, q2 = 0, q3 = 0;
    for (int r = blockIdx.x * 16 + rg; r < NNODES; r += gridDim.x * 16) {
        float4 v = *(const float4*)(agg + (size_t)r * 64 + c4);
        s0 += v.x; s1 += v.y; s2 += v.z; s3 += v.w;
        q0 = fmaf(v.x, v.x, q0); q1 = fmaf(v.y, v.y, q1);
        q2 = fmaf(v.z, v.z, q2); q3 = fmaf(v.w, v.w, q3);
    }
    __shared__ float ls[16 * 64], lq[16 * 64];
    ls[rg * 64 + c4 + 0] = s0; ls[rg * 64 + c4 + 1] = s1;
    ls[rg * 64 + c4 + 2] = s2; ls[rg * 64 + c4 + 3] = s3;
    lq[rg * 64 + c4 + 0] = q0; lq[rg * 64 + c4 + 1] = q1;
    lq[rg * 64 + c4 + 2] = q2; lq[rg * 64 + c4 + 3] = q3;
    __syncthreads();
    if (tid < 64) {
        float s = 0, q = 0;
#pragma unroll
        for (int g = 0; g < 16; ++g) {
            s += ls[g * 64 + tid];
            q += lq[g * 64 + tid];
        }
        unsafeAtomicAdd(&stats[tid], s);
        unsafeAtomicAdd(&stats[64 + tid], q);
    }
}

__global__ void k_bnparams(const float* __restrict__ stats, const float* __restrict__ g,
                           const float* __restrict__ be, float* __restrict__ scale,
                           float* __restrict__ shift) {
    int c = threadIdx.x;
    if (c < 64) {
        float mu = stats[c] * (1.0f / NNODES);
        float var = stats[64 + c] * (1.0f / NNODES) - mu * mu;
        float sc = g[c] * rsqrtf(var + EPSV);
        scale[c] = sc;
        shift[c] = fmaf(-mu, sc, be[c]);
    }
}

// ---------------------------------------------------------------- pool (sorted-batch run accumulation)
__global__ void k_pool(const float* __restrict__ agg, const float* __restrict__ scale,
                       const float* __restrict__ shift, const int* __restrict__ batch,
                       float* __restrict__ pooled) {
    const int tid = threadIdx.x;
    const int c = tid & 63, r = tid >> 6;
    const int i0 = blockIdx.x * PCH;
    const float sc = scale[c], sh = shift[c];
    float acc = 0.0f;
    int cur = -1;
#pragma unroll 4
    for (int k = 0; k < PCH / 4; ++k) {
        int i = i0 + k * 4 + r;
        if (i >= NNODES) break;
        int g = batch[i];
        if (g != cur) {
            if (cur >= 0) unsafeAtomicAdd(&pooled[cur * 64 + c], acc);
            acc = 0.0f;
            cur = g;
        }
        acc += fmaxf(fmaf(agg[(size_t)i * 64 + c], sc, sh), 0.0f);
    }
    if (cur >= 0) unsafeAtomicAdd(&pooled[cur * 64 + c], acc);
}

__global__ void k_final(const float* __restrict__ pooled, const int* __restrict__ gstart,
                        const int* __restrict__ gend, const float* __restrict__ Wfc,
                        const float* __restrict__ bfc, float* __restrict__ out) {
    __shared__ float p[64];
    __shared__ float ic;
    int g = blockIdx.x, tid = threadIdx.x;
    p[tid] = pooled[(size_t)g * 64 + tid];
    if (tid == 0) ic = 1.0f / fmaxf((float)(gend[g] - gstart[g]), 1.0f);
    __syncthreads();
    if (tid < DOUT) {
        float a = bfc[tid];
#pragma unroll 8
        for (int c = 0; c < 64; ++c) a = fmaf(p[c] * ic, Wfc[c * DOUT + tid], a);
        out[g * DOUT + tid] = a;
    }
}

// ---------------------------------------------------------------- launch
extern "C" void kernel_launch(void* const* d_in, const int* in_sizes, int n_in,
                              void* d_out, int out_size, void* d_ws, size_t ws_size,
                              hipStream_t stream) {
    const float* x = (const float*)d_in[0];
    const int* ei = (const int*)d_in[1];
    const int* batch = (const int*)d_in[2];
    const int* srcE = ei;
    const int* dstE = ei + NEDGES;
    const float* W[3] = {(const float*)d_in[3], (const float*)d_in[7], (const float*)d_in[11]};
    const float* B[3] = {(const float*)d_in[4], (const float*)d_in[8], (const float*)d_in[12]};
    const float* Gm[3] = {(const float*)d_in[5], (const float*)d_in[9], (const float*)d_in[13]};
    const float* Be[3] = {(const float*)d_in[6], (const float*)d_in[10], (const float*)d_in[14]};
    const float* Wfc = (const float*)d_in[15];
    const float* bfc = (const float*)d_in[16];
    float* out = (float*)d_out;

    float* f = (float*)d_ws;
    float* dinv = f;                            // [0, 100000)
    int* cntdeg = (int*)(f + 100000);           // [100000, 200000)
    int* rowptr = (int*)(f + 200000);           // [200000, 300016)
    // [300016, 400016) unused (was cursor)
    int* csr4 = (int*)(f + 400016);             // [400016, 2000016)  1.6M ints
    unsigned short* h = (unsigned short*)(f + 2000016);  // 6.4M bf16 = 3.2M floats: [2000016, 5200016)
    float* agg = f + 5200016;                   // [5200016, 11600016)  6.4M floats
    float* stats = agg + (size_t)NNODES * DH;   // 384 (3 layers x 128)
    float* scale = stats + 384;                 // 64
    float* shift = scale + 64;                  // 64
    float* pooled = shift + 64;                 // 32768
    int* gstart = (int*)(pooled + NG * DH);     // 512
    int* gend = gstart + NG;                    // 512
    short* wf = (short*)(gend + NG);            // 3*8192 shorts = 12288 floats
    int* bsum = (int*)((short*)wf + 24576);     // 400
    int* boff = bsum + 400;                     // 400
    int* bhist = boff + 400;                    // NEB*NB = 76636 -> ends 11724244
    int* boffs = bhist + NEB * NB;              // 76636 -> ends 11800880
    int2* staged = (int2*)(f + 11800882);       // even float offset; 1.6M int2 = 3.2M floats -> 15000882 (~60MB)

    k_zero<<<(NNODES + 255) / 256, 256, 0, stream>>>(cntdeg, pooled, gstart, gend, stats);
    k_count<<<(NEDGES / 2 + 255) / 256, 256, 0, stream>>>(dstE, cntdeg);
    k_scan1<<<SCAN_BLKS, 256, 0, stream>>>(cntdeg, bsum, dinv, batch, gstart, gend);
    k_scan2<<<1, 512, 0, stream>>>(bsum, boff);
    k_scan3<<<SCAN_BLKS, 256, 0, stream>>>(cntdeg, boff, rowptr);
    k_hist<<<NEB, 256, 0, stream>>>(dstE, bhist);
    k_bscan<<<NB, 512, 0, stream>>>(bhist, rowptr, boffs);
    k_bucket<<<NEB, 256, 0, stream>>>(srcE, dstE, boffs, staged);
    k_fill2<<<NB, 256, 0, stream>>>(staged, rowptr, csr4);
    k_wprep<<<6, 256, 0, stream>>>(W[0], W[1], W[2], wf);

    const int gemm_grid = (NNODES + 63) / 64;
    for (int l = 0; l < 3; ++l) {
        const float* in = (l == 0) ? x : agg;
        if (l == 0)
            k_mgemm<0><<<gemm_grid, 256, 0, stream>>>(in, wf + l * 8192, scale, shift, h);
        else
            k_mgemm<1><<<gemm_grid, 256, 0, stream>>>(in, wf + l * 8192, scale, shift, h);
        k_gather<<<(NNODES * 8 + 255) / 256, 256, 0, stream>>>((const uint4*)h, csr4, rowptr, dinv, B[l], agg);
        k_stats<<<512, 256, 0, stream>>>(agg, stats + l * 128);
        k_bnparams<<<1, 64, 0, stream>>>(stats + l * 128, Gm[l], Be[l], scale, shift);
    }

    k_pool<<<(NNODES + PCH - 1) / PCH, 256, 0, stream>>>(agg, scale, shift, batch, pooled);
    k_final<<<NG, 64, 0, stream>>>(pooled, gstart, gend, Wfc, bfc, out);
}

// Round 13
// 440.008 us; speedup vs baseline: 1.2950x; 1.1153x over previous
//
#include <hip/hip_runtime.h>

#define NNODES 100000
#define NEDGES 1600000
#define DH 64
#define NG 512
#define DOUT 10
#define EPSV 1e-5f
#define PCH 128        // nodes per pool block
#define NB 196         // dst buckets: ceil(100000/512)
#define EBLK 4096      // edges per histogram block
#define NEB 391        // ceil(NEDGES/EBLK)

typedef short bf16x8 __attribute__((ext_vector_type(8)));
typedef float f32x4 __attribute__((ext_vector_type(4)));

__device__ inline unsigned bf16_rne(float x) {
    unsigned u = __float_as_uint(x);
    return (u + 0x7fffu + ((u >> 16) & 1u)) >> 16;
}
__device__ inline float bflo(unsigned u) { return __uint_as_float(u << 16); }
__device__ inline float bfhi(unsigned u) { return __uint_as_float(u & 0xffff0000u); }

// ---------------------------------------------------------------- init
__global__ void k_zero(float* __restrict__ pooled, int* __restrict__ gstart,
                       int* __restrict__ gend, float* __restrict__ stats) {
    int i = blockIdx.x * 256 + threadIdx.x;
    if (i < NG * DH) pooled[i] = 0.0f;
    if (i < NG) { gstart[i] = 0; gend[i] = 0; }
    if (i < 384) stats[i] = 0.0f;  // 3 layers x (sum,sumsq)
}

// batch segment boundaries (sorted batch)
__global__ void k_batch(const int* __restrict__ batch, int* __restrict__ gstart,
                        int* __restrict__ gend) {
    int i = blockIdx.x * 256 + threadIdx.x;
    if (i >= NNODES) return;
    int g = batch[i];
    if (i == 0 || batch[i - 1] != g) gstart[g] = i;
    if (i == NNODES - 1 || batch[i + 1] != g) gend[g] = i + 1;
}

// ---------------------------------------------------------------- bucketed CSR build
// pass A: per edge-block histogram over 196 dst-buckets
__global__ void k_hist(const int* __restrict__ dstE, int* __restrict__ bhist) {
    __shared__ int lc[NB];
    int t = threadIdx.x, eb = blockIdx.x;
    for (int j = t; j < NB; j += 256) lc[j] = 0;
    __syncthreads();
    int e0 = eb * EBLK;
#pragma unroll
    for (int k = 0; k < EBLK / 256; ++k) {
        int e = e0 + k * 256 + t;
        if (e < NEDGES) atomicAdd(&lc[dstE[e] >> 9], 1);
    }
    __syncthreads();
    for (int j = t; j < NB; j += 256) bhist[eb * NB + j] = lc[j];
}

// pass B0: bucket totals -> exclusive scan -> bucketbase[NB+1]
__global__ void __launch_bounds__(256) k_btot(const int* __restrict__ bhist,
                                              int* __restrict__ bucketbase) {
    __shared__ int ps[256];
    int t = threadIdx.x;
    int s = 0;
    if (t < NB)
        for (int eb = 0; eb < NEB; ++eb) s += bhist[eb * NB + t];
    ps[t] = s;
    __syncthreads();
#pragma unroll
    for (int off = 1; off < 256; off <<= 1) {
        int u = (t >= off) ? ps[t - off] : 0;
        __syncthreads();
        ps[t] += u;
        __syncthreads();
    }
    if (t < NB) bucketbase[t] = ps[t] - s;
    if (t == 0) bucketbase[NB] = NEDGES;
}

// pass B1: per-bucket exclusive scan of block counts -> staging offsets
__global__ void __launch_bounds__(512) k_bscan(const int* __restrict__ bhist,
                                               const int* __restrict__ bucketbase,
                                               int* __restrict__ boffs) {
    __shared__ int ps[512];
    int b = blockIdx.x, t = threadIdx.x;
    int v = (t < NEB) ? bhist[t * NB + b] : 0;
    ps[t] = v;
    __syncthreads();
#pragma unroll
    for (int off = 1; off < 512; off <<= 1) {
        int u = (t >= off) ? ps[t - off] : 0;
        __syncthreads();
        ps[t] += u;
        __syncthreads();
    }
    if (t < NEB) boffs[t * NB + b] = bucketbase[b] + ps[t] - v;
}

// pass C: scatter (src,dst) into bucket-contiguous staging
__global__ void k_bucket(const int* __restrict__ srcE, const int* __restrict__ dstE,
                         const int* __restrict__ boffs, int2* __restrict__ staged) {
    __shared__ int lc[NB];
    __shared__ int lb[NB];
    int t = threadIdx.x, eb = blockIdx.x;
    for (int j = t; j < NB; j += 256) { lc[j] = 0; lb[j] = boffs[eb * NB + j]; }
    __syncthreads();
    int e0 = eb * EBLK;
#pragma unroll
    for (int k = 0; k < EBLK / 256; ++k) {
        int e = e0 + k * 256 + t;
        if (e < NEDGES) {
            int d = dstE[e], s = srcE[e];
            int b = d >> 9;
            int slot = atomicAdd(&lc[b], 1);
            staged[lb[b] + slot] = make_int2(s, d);
        }
    }
}

// pass D: bucket-owned: count degrees in LDS -> rowptr + dinv, then place srcs.
// Zero global atomics; all CSR-window writes from one CU.
__global__ void __launch_bounds__(512) k_fill3(const int2* __restrict__ staged,
                                               const int* __restrict__ bucketbase,
                                               int* __restrict__ rowptr,
                                               float* __restrict__ dinv,
                                               int* __restrict__ csr4) {
    __shared__ int cnt[512];
    __shared__ int ps[512];
    __shared__ int cur[512];
    int b = blockIdx.x, t = threadIdx.x;
    int n0 = b << 9;
    cnt[t] = 0;
    __syncthreads();
    int base = bucketbase[b], end = bucketbase[b + 1];
    for (int e = base + t; e < end; e += 512)
        atomicAdd(&cnt[staged[e].y - n0], 1);
    __syncthreads();
    int v = cnt[t];
    ps[t] = v;
    __syncthreads();
#pragma unroll
    for (int off = 1; off < 512; off <<= 1) {
        int u = (t >= off) ? ps[t - off] : 0;
        __syncthreads();
        ps[t] += u;
        __syncthreads();
    }
    int ex = base + ps[t] - v;
    int node = n0 + t;
    if (node < NNODES) {
        rowptr[node] = ex;
        dinv[node] = rsqrtf(1.0f + (float)v);
    }
    cur[t] = ex;
    __syncthreads();
    for (int e = base + t; e < end; e += 512) {
        int2 sd = staged[e];
        int pos = atomicAdd(&cur[sd.y - n0], 1);
        csr4[pos] = sd.x;
    }
    if (b == 0 && t == 0) rowptr[NNODES] = NEDGES;
}

// ---------------------------------------------------------------- W fragment prep
__global__ void k_wprep(const float* __restrict__ W0, const float* __restrict__ W1,
                        const float* __restrict__ W2, short* __restrict__ wf) {
    int t = blockIdx.x * 256 + threadIdx.x;  // [0, 1536)
    if (t >= 1536) return;
    int layer = t >> 9;
    int rem = t & 511;
    int ct = rem >> 7, ks = (rem >> 6) & 1, lane = rem & 63;
    const float* W = (layer == 0) ? W0 : (layer == 1) ? W1 : W2;
    short* hi = wf + layer * 8192 + rem * 8;
    short* lo = hi + 4096;
#pragma unroll
    for (int i = 0; i < 8; ++i) {
        int k = ks * 32 + ((lane >> 4) << 3) + i;
        int n = ct * 16 + (lane & 15);
        float v = W[k * 64 + n];
        unsigned h = bf16_rne(v);
        float fh = __uint_as_float(h << 16);
        unsigned l = bf16_rne(v - fh);
        hi[i] = (short)h;
        lo[i] = (short)l;
    }
}

// ---------------------------------------------------------------- MFMA GEMM (bf16 output)
template <int AFFINE>
__global__ void __launch_bounds__(256) k_mgemm(const float* __restrict__ in,
        const short* __restrict__ wf, const float* __restrict__ scale,
        const float* __restrict__ shift, unsigned short* __restrict__ out) {
    const int tid = threadIdx.x;
    const int wv = tid >> 6, l = tid & 63;
    const int r0 = blockIdx.x * 64 + wv * 16;
    const int row = r0 + (l & 15);
    const int kq = (l >> 4) << 3;  // 0,8,16,24

    float a[2][8];
    if (row < NNODES) {
        const float* rp = in + (size_t)row * 64 + kq;
        *(float4*)&a[0][0] = *(const float4*)(rp);
        *(float4*)&a[0][4] = *(const float4*)(rp + 4);
        *(float4*)&a[1][0] = *(const float4*)(rp + 32);
        *(float4*)&a[1][4] = *(const float4*)(rp + 36);
    } else {
#pragma unroll
        for (int ks = 0; ks < 2; ++ks)
#pragma unroll
            for (int i = 0; i < 8; ++i) a[ks][i] = 0.0f;
    }
    if (AFFINE) {
#pragma unroll
        for (int ks = 0; ks < 2; ++ks) {
            float4 sc0 = *(const float4*)(scale + kq + ks * 32);
            float4 sc1 = *(const float4*)(scale + kq + ks * 32 + 4);
            float4 sh0 = *(const float4*)(shift + kq + ks * 32);
            float4 sh1 = *(const float4*)(shift + kq + ks * 32 + 4);
            a[ks][0] = fmaxf(fmaf(a[ks][0], sc0.x, sh0.x), 0.0f);
            a[ks][1] = fmaxf(fmaf(a[ks][1], sc0.y, sh0.y), 0.0f);
            a[ks][2] = fmaxf(fmaf(a[ks][2], sc0.z, sh0.z), 0.0f);
            a[ks][3] = fmaxf(fmaf(a[ks][3], sc0.w, sh0.w), 0.0f);
            a[ks][4] = fmaxf(fmaf(a[ks][4], sc1.x, sh1.x), 0.0f);
            a[ks][5] = fmaxf(fmaf(a[ks][5], sc1.y, sh1.y), 0.0f);
            a[ks][6] = fmaxf(fmaf(a[ks][6], sc1.z, sh1.z), 0.0f);
            a[ks][7] = fmaxf(fmaf(a[ks][7], sc1.w, sh1.w), 0.0f);
        }
    }

    bf16x8 ah[2], al[2];
#pragma unroll
    for (int ks = 0; ks < 2; ++ks)
#pragma unroll
        for (int i = 0; i < 8; ++i) {
            unsigned h = bf16_rne(a[ks][i]);
            float fh = __uint_as_float(h << 16);
            ah[ks][i] = (short)h;
            al[ks][i] = (short)bf16_rne(a[ks][i] - fh);
        }

    const int rb = r0 + ((l >> 4) << 2);
    const int cb = l & 15;
#pragma unroll
    for (int ct = 0; ct < 4; ++ct) {
        const short* base = wf + (ct * 128 + l) * 8;
        bf16x8 wh0 = *(const bf16x8*)(base);
        bf16x8 wh1 = *(const bf16x8*)(base + 64 * 8);
        bf16x8 wl0 = *(const bf16x8*)(base + 4096);
        bf16x8 wl1 = *(const bf16x8*)(base + 4096 + 64 * 8);
        f32x4 acc = {0.0f, 0.0f, 0.0f, 0.0f};
        acc = __builtin_amdgcn_mfma_f32_16x16x32_bf16(ah[0], wh0, acc, 0, 0, 0);
        acc = __builtin_amdgcn_mfma_f32_16x16x32_bf16(ah[1], wh1, acc, 0, 0, 0);
        acc = __builtin_amdgcn_mfma_f32_16x16x32_bf16(al[0], wh0, acc, 0, 0, 0);
        acc = __builtin_amdgcn_mfma_f32_16x16x32_bf16(al[1], wh1, acc, 0, 0, 0);
        acc = __builtin_amdgcn_mfma_f32_16x16x32_bf16(ah[0], wl0, acc, 0, 0, 0);
        acc = __builtin_amdgcn_mfma_f32_16x16x32_bf16(ah[1], wl1, acc, 0, 0, 0);
        int n = ct * 16 + cb;
#pragma unroll
        for (int r = 0; r < 4; ++r)
            if (rb + r < NNODES) out[(size_t)(rb + r) * 64 + n] = (unsigned short)bf16_rne(acc[r]);
    }
}

// ---------------------------------------------------------------- gather (CSR src-only, bf16 h)
// agg[i] = bias + dv*( dv*h_i + sum_e dinv[src_e]*h[src_e] ),  dv = dinv[i]
__global__ void k_gather(const uint4* __restrict__ h, const int* __restrict__ csr4,
                         const int* __restrict__ rowptr, const float* __restrict__ dinv,
                         const float* __restrict__ bias, float* __restrict__ agg) {
    int t = blockIdx.x * 256 + threadIdx.x;
    int i = t >> 3, q = t & 7;
    if (i >= NNODES) return;
    float dv = dinv[i];
    uint4 hv = h[(size_t)i * 8 + q];
    float A[8], B[8];
    A[0] = bflo(hv.x) * dv; A[1] = bfhi(hv.x) * dv;
    A[2] = bflo(hv.y) * dv; A[3] = bfhi(hv.y) * dv;
    A[4] = bflo(hv.z) * dv; A[5] = bfhi(hv.z) * dv;
    A[6] = bflo(hv.w) * dv; A[7] = bfhi(hv.w) * dv;
#pragma unroll
    for (int k = 0; k < 8; ++k) B[k] = 0.0f;

    int e0 = rowptr[i], e1 = rowptr[i + 1];
    int e = e0;
    for (; e + 4 <= e1; e += 4) {
        int sa = csr4[e], sb = csr4[e + 1], sc = csr4[e + 2], sd = csr4[e + 3];
        float na = dinv[sa], nb = dinv[sb], nc = dinv[sc], nd = dinv[sd];
        uint4 va = h[(size_t)sa * 8 + q];
        uint4 vb = h[(size_t)sb * 8 + q];
        uint4 vc = h[(size_t)sc * 8 + q];
        uint4 vd = h[(size_t)sd * 8 + q];
        A[0] = fmaf(bflo(va.x), na, A[0]); A[1] = fmaf(bfhi(va.x), na, A[1]);
        A[2] = fmaf(bflo(va.y), na, A[2]); A[3] = fmaf(bfhi(va.y), na, A[3]);
        A[4] = fmaf(bflo(va.z), na, A[4]); A[5] = fmaf(bfhi(va.z), na, A[5]);
        A[6] = fmaf(bflo(va.w), na, A[6]); A[7] = fmaf(bfhi(va.w), na, A[7]);
        B[0] = fmaf(bflo(vb.x), nb, B[0]); B[1] = fmaf(bfhi(vb.x), nb, B[1]);
        B[2] = fmaf(bflo(vb.y), nb, B[2]); B[3] = fmaf(bfhi(vb.y), nb, B[3]);
        B[4] = fmaf(bflo(vb.z), nb, B[4]); B[5] = fmaf(bfhi(vb.z), nb, B[5]);
        B[6] = fmaf(bflo(vb.w), nb, B[6]); B[7] = fmaf(bfhi(vb.w), nb, B[7]);
        A[0] = fmaf(bflo(vc.x), nc, A[0]); A[1] = fmaf(bfhi(vc.x), nc, A[1]);
        A[2] = fmaf(bflo(vc.y), nc, A[2]); A[3] = fmaf(bfhi(vc.y), nc, A[3]);
        A[4] = fmaf(bflo(vc.z), nc, A[4]); A[5] = fmaf(bfhi(vc.z), nc, A[5]);
        A[6] = fmaf(bflo(vc.w), nc, A[6]); A[7] = fmaf(bfhi(vc.w), nc, A[7]);
        B[0] = fmaf(bflo(vd.x), nd, B[0]); B[1] = fmaf(bfhi(vd.x), nd, B[1]);
        B[2] = fmaf(bflo(vd.y), nd, B[2]); B[3] = fmaf(bfhi(vd.y), nd, B[3]);
        B[4] = fmaf(bflo(vd.z), nd, B[4]); B[5] = fmaf(bfhi(vd.z), nd, B[5]);
        B[6] = fmaf(bflo(vd.w), nd, B[6]); B[7] = fmaf(bfhi(vd.w), nd, B[7]);
    }
    for (; e + 2 <= e1; e += 2) {
        int sa = csr4[e], sb = csr4[e + 1];
        float na = dinv[sa], nb = dinv[sb];
        uint4 va = h[(size_t)sa * 8 + q];
        uint4 vb = h[(size_t)sb * 8 + q];
        A[0] = fmaf(bflo(va.x), na, A[0]); A[1] = fmaf(bfhi(va.x), na, A[1]);
        A[2] = fmaf(bflo(va.y), na, A[2]); A[3] = fmaf(bfhi(va.y), na, A[3]);
        A[4] = fmaf(bflo(va.z), na, A[4]); A[5] = fmaf(bfhi(va.z), na, A[5]);
        A[6] = fmaf(bflo(va.w), na, A[6]); A[7] = fmaf(bfhi(va.w), na, A[7]);
        B[0] = fmaf(bflo(vb.x), nb, B[0]); B[1] = fmaf(bfhi(vb.x), nb, B[1]);
        B[2] = fmaf(bflo(vb.y), nb, B[2]); B[3] = fmaf(bfhi(vb.y), nb, B[3]);
        B[4] = fmaf(bflo(vb.z), nb, B[4]); B[5] = fmaf(bfhi(vb.z), nb, B[5]);
        B[6] = fmaf(bflo(vb.w), nb, B[6]); B[7] = fmaf(bfhi(vb.w), nb, B[7]);
    }
    if (e < e1) {
        int sa = csr4[e];
        float na = dinv[sa];
        uint4 va = h[(size_t)sa * 8 + q];
        A[0] = fmaf(bflo(va.x), na, A[0]); A[1] = fmaf(bfhi(va.x), na, A[1]);
        A[2] = fmaf(bflo(va.y), na, A[2]); A[3] = fmaf(bfhi(va.y), na, A[3]);
        A[4] = fmaf(bflo(va.z), na, A[4]); A[5] = fmaf(bfhi(va.z), na, A[5]);
        A[6] = fmaf(bflo(va.w), na, A[6]); A[7] = fmaf(bfhi(va.w), na, A[7]);
    }
    float4 b0 = ((const float4*)bias)[q * 2];
    float4 b1 = ((const float4*)bias)[q * 2 + 1];
    float4 r0, r1;
    r0.x = fmaf(A[0] + B[0], dv, b0.x); r0.y = fmaf(A[1] + B[1], dv, b0.y);
    r0.z = fmaf(A[2] + B[2], dv, b0.z); r0.w = fmaf(A[3] + B[3], dv, b0.w);
    r1.x = fmaf(A[4] + B[4], dv, b1.x); r1.y = fmaf(A[5] + B[5], dv, b1.y);
    r1.z = fmaf(A[6] + B[6], dv, b1.z); r1.w = fmaf(A[7] + B[7], dv, b1.w);
    ((float4*)agg)[(size_t)i * 16 + q * 2] = r0;
    ((float4*)agg)[(size_t)i * 16 + q * 2 + 1] = r1;
}

// ---------------------------------------------------------------- BN stats (float4 vectorized)
__global__ void k_stats(const float* __restrict__ agg, float* __restrict__ stats) {
    const int tid = threadIdx.x;
    const int c4 = (tid & 15) * 4;      // feature group
    const int rg = tid >> 4;            // row subgroup 0..15
    float s0 = 0, s1 = 0, s2 = 0, s3 = 0;
    float q0 = 0, q1 = 0, q2 = 0, q3 = 0;
    for (int r = blockIdx.x * 16 + rg; r < NNODES; r += gridDim.x * 16) {
        float4 v = *(const float4*)(agg + (size_t)r * 64 + c4);
        s0 += v.x; s1 += v.y; s2 += v.z; s3 += v.w;
        q0 = fmaf(v.x, v.x, q0); q1 = fmaf(v.y, v.y, q1);
        q2 = fmaf(v.z, v.z, q2); q3 = fmaf(v.w, v.w, q3);
    }
    __shared__ float ls[16 * 64], lq[16 * 64];
    ls[rg * 64 + c4 + 0] = s0; ls[rg * 64 + c4 + 1] = s1;
    ls[rg * 64 + c4 + 2] = s2; ls[rg * 64 + c4 + 3] = s3;
    lq[rg * 64 + c4 + 0] = q0; lq[rg * 64 + c4 + 1] = q1;
    lq[rg * 64 + c4 + 2] = q2; lq[rg * 64 + c4 + 3] = q3;
    __syncthreads();
    if (tid < 64) {
        float s = 0, q = 0;
#pragma unroll
        for (int g = 0; g < 16; ++g) {
            s += ls[g * 64 + tid];
            q += lq[g * 64 + tid];
        }
        unsafeAtomicAdd(&stats[tid], s);
        unsafeAtomicAdd(&stats[64 + tid], q);
    }
}

__global__ void k_bnparams(const float* __restrict__ stats, const float* __restrict__ g,
                           const float* __restrict__ be, float* __restrict__ scale,
                           float* __restrict__ shift) {
    int c = threadIdx.x;
    if (c < 64) {
        float mu = stats[c] * (1.0f / NNODES);
        float var = stats[64 + c] * (1.0f / NNODES) - mu * mu;
        float sc = g[c] * rsqrtf(var + EPSV);
        scale[c] = sc;
        shift[c] = fmaf(-mu, sc, be[c]);
    }
}

// ---------------------------------------------------------------- pool (sorted-batch run accumulation)
__global__ void k_pool(const float* __restrict__ agg, const float* __restrict__ scale,
                       const float* __restrict__ shift, const int* __restrict__ batch,
                       float* __restrict__ pooled) {
    const int tid = threadIdx.x;
    const int c = tid & 63, r = tid >> 6;
    const int i0 = blockIdx.x * PCH;
    const float sc = scale[c], sh = shift[c];
    float acc = 0.0f;
    int cur = -1;
#pragma unroll 4
    for (int k = 0; k < PCH / 4; ++k) {
        int i = i0 + k * 4 + r;
        if (i >= NNODES) break;
        int g = batch[i];
        if (g != cur) {
            if (cur >= 0) unsafeAtomicAdd(&pooled[cur * 64 + c], acc);
            acc = 0.0f;
            cur = g;
        }
        acc += fmaxf(fmaf(agg[(size_t)i * 64 + c], sc, sh), 0.0f);
    }
    if (cur >= 0) unsafeAtomicAdd(&pooled[cur * 64 + c], acc);
}

__global__ void k_final(const float* __restrict__ pooled, const int* __restrict__ gstart,
                        const int* __restrict__ gend, const float* __restrict__ Wfc,
                        const float* __restrict__ bfc, float* __restrict__ out) {
    __shared__ float p[64];
    __shared__ float ic;
    int g = blockIdx.x, tid = threadIdx.x;
    p[tid] = pooled[(size_t)g * 64 + tid];
    if (tid == 0) ic = 1.0f / fmaxf((float)(gend[g] - gstart[g]), 1.0f);
    __syncthreads();
    if (tid < DOUT) {
        float a = bfc[tid];
#pragma unroll 8
        for (int c = 0; c < 64; ++c) a = fmaf(p[c] * ic, Wfc[c * DOUT + tid], a);
        out[g * DOUT + tid] = a;
    }
}

// ---------------------------------------------------------------- launch
extern "C" void kernel_launch(void* const* d_in, const int* in_sizes, int n_in,
                              void* d_out, int out_size, void* d_ws, size_t ws_size,
                              hipStream_t stream) {
    const float* x = (const float*)d_in[0];
    const int* ei = (const int*)d_in[1];
    const int* batch = (const int*)d_in[2];
    const int* srcE = ei;
    const int* dstE = ei + NEDGES;
    const float* W[3] = {(const float*)d_in[3], (const float*)d_in[7], (const float*)d_in[11]};
    const float* B[3] = {(const float*)d_in[4], (const float*)d_in[8], (const float*)d_in[12]};
    const float* Gm[3] = {(const float*)d_in[5], (const float*)d_in[9], (const float*)d_in[13]};
    const float* Be[3] = {(const float*)d_in[6], (const float*)d_in[10], (const float*)d_in[14]};
    const float* Wfc = (const float*)d_in[15];
    const float* bfc = (const float*)d_in[16];
    float* out = (float*)d_out;

    float* f = (float*)d_ws;
    float* dinv = f;                            // [0, 100000)
    int* rowptr = (int*)(f + 200000);           // [200000, 300016)
    int* csr4 = (int*)(f + 400016);             // [400016, 2000016)  1.6M ints
    unsigned short* h = (unsigned short*)(f + 2000016);  // 6.4M bf16 = 3.2M floats: [2000016, 5200016)
    float* agg = f + 5200016;                   // [5200016, 11600016)  6.4M floats
    float* stats = agg + (size_t)NNODES * DH;   // 384 (3 layers x 128)
    float* scale = stats + 384;                 // 64
    float* shift = scale + 64;                  // 64
    float* pooled = shift + 64;                 // 32768
    int* gstart = (int*)(pooled + NG * DH);     // 512
    int* gend = gstart + NG;                    // 512
    short* wf = (short*)(gend + NG);            // 3*8192 shorts = 12288 floats -> ends 11646608
    int* bucketbase = (int*)((short*)wf + 24576);  // 256 -> ends 11646864
    int* bhist = bucketbase + 256;              // NEB*NB = 76636 -> ends 11723500
    int* boffs = bhist + NEB * NB;              // 76636 -> ends 11800136
    int2* staged = (int2*)(f + 11800882);       // 1.6M int2 = 3.2M floats -> ends 15000882 (~60MB)

    k_zero<<<(NG * DH + 255) / 256, 256, 0, stream>>>(pooled, gstart, gend, stats);
    k_batch<<<(NNODES + 255) / 256, 256, 0, stream>>>(batch, gstart, gend);
    k_hist<<<NEB, 256, 0, stream>>>(dstE, bhist);
    k_btot<<<1, 256, 0, stream>>>(bhist, bucketbase);
    k_bscan<<<NB, 512, 0, stream>>>(bhist, bucketbase, boffs);
    k_bucket<<<NEB, 256, 0, stream>>>(srcE, dstE, boffs, staged);
    k_fill3<<<NB, 512, 0, stream>>>(staged, bucketbase, rowptr, dinv, csr4);
    k_wprep<<<6, 256, 0, stream>>>(W[0], W[1], W[2], wf);

    const int gemm_grid = (NNODES + 63) / 64;
    for (int l = 0; l < 3; ++l) {
        const float* in = (l == 0) ? x : agg;
        if (l == 0)
            k_mgemm<0><<<gemm_grid, 256, 0, stream>>>(in, wf + l * 8192, scale, shift, h);
        else
            k_mgemm<1><<<gemm_grid, 256, 0, stream>>>(in, wf + l * 8192, scale, shift, h);
        k_gather<<<(NNODES * 8 + 255) / 256, 256, 0, stream>>>((const uint4*)h, csr4, rowptr, dinv, B[l], agg);
        k_stats<<<512, 256, 0, stream>>>(agg, stats + l * 128);
        k_bnparams<<<1, 64, 0, stream>>>(stats + l * 128, Gm[l], Be[l], scale, shift);
    }

    k_pool<<<(NNODES + PCH - 1) / PCH, 256, 0, stream>>>(agg, scale, shift, batch, pooled);
    k_final<<<NG, 64, 0, stream>>>(pooled, gstart, gend, Wfc, bfc, out);
}